// Round 2
// baseline (2524.610 us; speedup 1.0000x reference)
//
#include <hip/hip_runtime.h>
#include <stdint.h>

#define B 8
#define S 128
#define D 512
#define NIN 1024
#define NOUT 1024
#define T 32

// ---------------------------------------------------------------------------
// Generic fp32 tiled GEMM: C[M,N] = maybe_relu(A[M,K] @ Bm[K,N] + bias[N])
// 64x64 tile, BK=16, 256 threads, 4x4 micro-tile.
// ---------------------------------------------------------------------------
__global__ __launch_bounds__(256) void k_gemm(const float* __restrict__ A,
                                              const float* __restrict__ Bm,
                                              const float* __restrict__ bias,
                                              float* __restrict__ C,
                                              int M, int N, int K, int relu)
{
    __shared__ float As[16][64];
    __shared__ float Bs[16][64];
    const int tid = threadIdx.x;
    const int bx = blockIdx.x, by = blockIdx.y;
    const int tx = tid & 15, ty = tid >> 4;
    const int ar = tid >> 2, ak = (tid & 3) << 2;   // A tile: row 0..63, k 0..15 (x4)
    const int bk = tid >> 4, bc = (tid & 15) << 2;  // B tile: k 0..15, col 0..63 (x4)
    float acc[4][4] = {{0.f,0.f,0.f,0.f},{0.f,0.f,0.f,0.f},
                       {0.f,0.f,0.f,0.f},{0.f,0.f,0.f,0.f}};
    for (int k0 = 0; k0 < K; k0 += 16) {
        float4 a4 = *(const float4*)(A + (size_t)(by*64 + ar)*K + k0 + ak);
        float4 b4 = *(const float4*)(Bm + (size_t)(k0 + bk)*N + bx*64 + bc);
        __syncthreads();
        As[ak+0][ar] = a4.x; As[ak+1][ar] = a4.y;
        As[ak+2][ar] = a4.z; As[ak+3][ar] = a4.w;
        *(float4*)&Bs[bk][bc] = b4;
        __syncthreads();
        #pragma unroll
        for (int kk = 0; kk < 16; ++kk) {
            float4 av = *(const float4*)&As[kk][ty << 2];
            float4 bv = *(const float4*)&Bs[kk][tx << 2];
            acc[0][0] = fmaf(av.x, bv.x, acc[0][0]);
            acc[0][1] = fmaf(av.x, bv.y, acc[0][1]);
            acc[0][2] = fmaf(av.x, bv.z, acc[0][2]);
            acc[0][3] = fmaf(av.x, bv.w, acc[0][3]);
            acc[1][0] = fmaf(av.y, bv.x, acc[1][0]);
            acc[1][1] = fmaf(av.y, bv.y, acc[1][1]);
            acc[1][2] = fmaf(av.y, bv.z, acc[1][2]);
            acc[1][3] = fmaf(av.y, bv.w, acc[1][3]);
            acc[2][0] = fmaf(av.z, bv.x, acc[2][0]);
            acc[2][1] = fmaf(av.z, bv.y, acc[2][1]);
            acc[2][2] = fmaf(av.z, bv.z, acc[2][2]);
            acc[2][3] = fmaf(av.z, bv.w, acc[2][3]);
            acc[3][0] = fmaf(av.w, bv.x, acc[3][0]);
            acc[3][1] = fmaf(av.w, bv.y, acc[3][1]);
            acc[3][2] = fmaf(av.w, bv.z, acc[3][2]);
            acc[3][3] = fmaf(av.w, bv.w, acc[3][3]);
        }
    }
    const int row0 = by*64 + (ty << 2), col0 = bx*64 + (tx << 2);
    float4 bb = *(const float4*)(bias + col0);
    #pragma unroll
    for (int i = 0; i < 4; ++i) {
        float4 o;
        o.x = acc[i][0] + bb.x; o.y = acc[i][1] + bb.y;
        o.z = acc[i][2] + bb.z; o.w = acc[i][3] + bb.w;
        if (relu) {
            o.x = fmaxf(o.x, 0.f); o.y = fmaxf(o.y, 0.f);
            o.z = fmaxf(o.z, 0.f); o.w = fmaxf(o.w, 0.f);
        }
        *(float4*)(C + (size_t)(row0 + i)*N + col0) = o;
    }
}

// ---------------------------------------------------------------------------
// Input-population LIF: each thread = one (b, n_in) neuron, runs all 4096
// steps. Wave = 64 consecutive n of same b -> __ballot emits u64 spike mask.
// masks layout: [b][tg=0..4095][w=0..15] u64
// ---------------------------------------------------------------------------
__global__ __launch_bounds__(256) void k_lif_in(const float* __restrict__ snn,
                                                unsigned long long* __restrict__ masks,
                                                unsigned int* __restrict__ counters)
{
    const int tid  = blockIdx.x * 256 + threadIdx.x;  // 0..8191
    const int w    = tid >> 6;                        // wave 0..127
    const int lane = tid & 63;
    const int b    = w >> 4;
    const int nb   = w & 15;                          // u64-word index
    const int n    = (nb << 6) + lane;
    float v = 0.f;
    int cnt = 0;
    const float* cur = snn + (size_t)(b * S) * NIN + n;
    unsigned long long* mrow = masks + (size_t)(b * (S*T)) * 16 + nb;
    for (int s = 0; s < S; ++s) {
        const float I = cur[(size_t)s * NIN];
        #pragma unroll
        for (int t = 0; t < T; ++t) {
            v = __fadd_rn(__fmul_rn(0.9f, v), I);
            const bool sp = (v >= 1.0f);
            const unsigned long long m = __ballot(sp);
            v = sp ? (v - 1.0f) : v;
            cnt += sp ? 1 : 0;
            if (lane == 0) mrow[(size_t)(s*T + t) * 16] = m;
        }
    }
    atomicAdd(counters, (unsigned int)cnt);
}

// ---------------------------------------------------------------------------
// Spike-gather: block = one (b, position, 16-timestep half). Builds per-row
// 16-bit t-masks, compacts active rows into an ordered LDS list (n-ascending,
// so the fp add order matches previous passing round), then a branchless
// software-pipelined loop: prefetch next W_conn row while accumulating the
// current one. acc = 16 x float4 = 64 VGPRs -> stays in arch VGPRs.
// ---------------------------------------------------------------------------
__global__ __launch_bounds__(256, 4) void k_conn(const unsigned long long* __restrict__ masks,
                                                 const float* __restrict__ Wc,
                                                 float* __restrict__ Iout,
                                                 int s0, int P)
{
    const int idx  = blockIdx.x;       // 0 .. B*P*2-1
    const int half = idx & 1;
    const int bs   = idx >> 1;
    const int b    = bs / P;
    const int sl   = bs - b * P;
    const int s    = s0 + sl;
    const int tid  = threadIdx.x;
    const int sh   = half * 16;

    __shared__ unsigned short tm[NIN];
    __shared__ unsigned int   list[NIN + 1];
    __shared__ int            lcount;

    // build 16-bit per-row timestep masks for this half
    const unsigned long long* mbase =
        masks + ((size_t)(b * (S*T) + s * T + sh)) * 16;
    #pragma unroll
    for (int i = 0; i < 4; ++i) {
        const int n = (tid << 2) + i;
        const int wq = n >> 6, bit = n & 63;
        unsigned int vm = 0;
        #pragma unroll
        for (int t = 0; t < 16; ++t)
            vm |= (unsigned int)((mbase[t * 16 + wq] >> bit) & 1ULL) << t;
        tm[n] = (unsigned short)vm;
    }
    __syncthreads();

    // wave 0: ordered compaction of active rows into list[] (n-ascending)
    if (tid < 64) {
        int cnt = 0;
        for (int c = 0; c < 16; ++c) {
            const int n = c * 64 + tid;
            const unsigned int m16 = tm[n];
            const unsigned long long act = __ballot(m16 != 0);
            const int pre = __popcll(act & ((1ULL << tid) - 1ULL));
            if (m16) list[cnt + pre] = (m16 << 16) | (unsigned int)n;
            cnt += __popcll(act);
        }
        if (tid == 0) {
            lcount = cnt;
            list[cnt] = 0u;   // sentinel (n=0, mask=0): safe dummy prefetch
        }
    }
    __syncthreads();

    const int len = lcount;
    float4 acc[16];
    #pragma unroll
    for (int t = 0; t < 16; ++t) acc[t] = make_float4(0.f, 0.f, 0.f, 0.f);

    const float* wp = Wc + (tid << 2);
    if (len > 0) {
        unsigned int u = list[0];
        float4 wv = *(const float4*)(wp + (size_t)(u & 0xffffu) * NOUT);
        for (int i = 0; i < len; ++i) {
            const unsigned int nu = list[i + 1];
            const float4 nwv = *(const float4*)(wp + (size_t)(nu & 0xffffu) * NOUT);
            const unsigned int m =
                (unsigned int)__builtin_amdgcn_readfirstlane((int)(u >> 16));
            #pragma unroll
            for (int t = 0; t < 16; ++t) {
                if (m & (1u << t)) {
                    acc[t].x += wv.x; acc[t].y += wv.y;
                    acc[t].z += wv.z; acc[t].w += wv.w;
                }
            }
            u = nu; wv = nwv;
        }
    }

    const int Tc = P * T;
    float* obase = Iout + ((size_t)b * Tc + (size_t)sl * T + sh) * NOUT + (tid << 2);
    #pragma unroll
    for (int t = 0; t < 16; ++t)
        *(float4*)(obase + (size_t)t * NOUT) = acc[t];
}

// ---------------------------------------------------------------------------
// Output-population LIF: thread = one (b, n_out) neuron; walks the chunk's
// timesteps sequentially, accumulating per-position spike counts.
// ---------------------------------------------------------------------------
__global__ __launch_bounds__(256) void k_lif_out(const float* __restrict__ Iout,
                                                 float* __restrict__ vstate,
                                                 float* __restrict__ sacc_out,
                                                 unsigned int* __restrict__ counters,
                                                 int s0, int P, int init)
{
    const int tid = blockIdx.x * 256 + threadIdx.x;   // 0..8191
    const int b = tid >> 10, n = tid & (NOUT - 1);
    const int Tc = P * T;
    float v = init ? 0.f : vstate[tid];
    const float* ip = Iout + (size_t)b * Tc * NOUT + n;
    int cnt = 0;
    for (int sl = 0; sl < P; ++sl) {
        float sacc = 0.f;
        #pragma unroll
        for (int t = 0; t < T; ++t) {
            const float I = ip[(size_t)(sl*T + t) * NOUT];
            v = __fadd_rn(__fmul_rn(0.9f, v), I);
            const bool sp = (v >= 1.0f);
            v = sp ? (v - 1.0f) : v;
            sacc += sp ? 1.f : 0.f;
            cnt += sp ? 1 : 0;
        }
        sacc_out[(size_t)(b*S + s0 + sl) * NOUT + n] = sacc;
    }
    vstate[tid] = v;
    atomicAdd(counters + 1, (unsigned int)cnt);
}

__global__ void k_init(unsigned int* c)
{
    if (threadIdx.x < 2) c[threadIdx.x] = 0u;
}

__global__ void k_rate(const unsigned int* __restrict__ c, float* __restrict__ out)
{
    if (threadIdx.x == 0 && blockIdx.x == 0) {
        const float total = (float)c[0] + (float)c[1];
        out[0] = total / (float)(B * S * (NIN + NOUT) * T);
    }
}

// ---------------------------------------------------------------------------
extern "C" void kernel_launch(void* const* d_in, const int* in_sizes, int n_in,
                              void* d_out, int out_size, void* d_ws, size_t ws_size,
                              hipStream_t stream)
{
    const float* E    = (const float*)d_in[0];
    const float* Win  = (const float*)d_in[1];
    const float* bin  = (const float*)d_in[2];
    const float* Wc   = (const float*)d_in[3];
    const float* Wout = (const float*)d_in[4];
    const float* bout = (const float*)d_in[5];
    float* out = (float*)d_out;

    char* w = (char*)d_ws;
    float* snn              = (float*)(w);                          // 4 MB
    unsigned long long* msk = (unsigned long long*)(w + (4 << 20)); // 4 MB
    float* sacc             = (float*)(w + (8 << 20));              // 4 MB
    float* vst              = (float*)(w + (12 << 20));             // 32 KB
    unsigned int* cnt       = (unsigned int*)(w + (12 << 20) + (64 << 10));
    float* Iout             = (float*)(w + (13 << 20));

    const size_t base = (size_t)13 << 20;
    const size_t avail = (ws_size > base) ? (ws_size - base) : 0;
    int P = 1;
    if      (avail >= (size_t)B * 128 * T * NOUT * 4) P = 128;
    else if (avail >= (size_t)B *  16 * T * NOUT * 4) P = 16;
    else if (avail >= (size_t)B *   4 * T * NOUT * 4) P = 4;

    k_init<<<1, 64, 0, stream>>>(cnt);

    dim3 g1(NIN / 64, (B * S) / 64);
    k_gemm<<<g1, 256, 0, stream>>>(E, Win, bin, snn, B * S, NIN, D, 1);

    k_lif_in<<<32, 256, 0, stream>>>(snn, msk, cnt);

    for (int c = 0; c < S / P; ++c) {
        k_conn<<<B * P * 2, 256, 0, stream>>>(msk, Wc, Iout, c * P, P);
        k_lif_out<<<32, 256, 0, stream>>>(Iout, vst, sacc, cnt, c * P, P, c == 0 ? 1 : 0);
    }

    dim3 g2(D / 64, (B * S) / 64);
    k_gemm<<<g2, 256, 0, stream>>>(sacc, Wout, bout, out, B * S, D, NOUT, 0);

    k_rate<<<1, 64, 0, stream>>>(cnt, out + (size_t)B * S * D);
}

// Round 3
// 722.138 us; speedup vs baseline: 3.4960x; 3.4960x over previous
//
#include <hip/hip_runtime.h>
#include <stdint.h>

#define B 8
#define S 128
#define D 512
#define NIN 1024
#define NOUT 1024
#define T 32

typedef __attribute__((ext_vector_type(8))) short short8;
typedef __attribute__((ext_vector_type(4))) float floatx4;

// ---------------------------------------------------------------------------
// Generic fp32 tiled GEMM: C[M,N] = maybe_relu(A[M,K] @ Bm[K,N] + bias[N])
// ---------------------------------------------------------------------------
__global__ __launch_bounds__(256) void k_gemm(const float* __restrict__ A,
                                              const float* __restrict__ Bm,
                                              const float* __restrict__ bias,
                                              float* __restrict__ C,
                                              int M, int N, int K, int relu)
{
    __shared__ float As[16][64];
    __shared__ float Bs[16][64];
    const int tid = threadIdx.x;
    const int bx = blockIdx.x, by = blockIdx.y;
    const int tx = tid & 15, ty = tid >> 4;
    const int ar = tid >> 2, ak = (tid & 3) << 2;
    const int bk = tid >> 4, bc = (tid & 15) << 2;
    float acc[4][4] = {{0.f,0.f,0.f,0.f},{0.f,0.f,0.f,0.f},
                       {0.f,0.f,0.f,0.f},{0.f,0.f,0.f,0.f}};
    for (int k0 = 0; k0 < K; k0 += 16) {
        float4 a4 = *(const float4*)(A + (size_t)(by*64 + ar)*K + k0 + ak);
        float4 b4 = *(const float4*)(Bm + (size_t)(k0 + bk)*N + bx*64 + bc);
        __syncthreads();
        As[ak+0][ar] = a4.x; As[ak+1][ar] = a4.y;
        As[ak+2][ar] = a4.z; As[ak+3][ar] = a4.w;
        *(float4*)&Bs[bk][bc] = b4;
        __syncthreads();
        #pragma unroll
        for (int kk = 0; kk < 16; ++kk) {
            float4 av = *(const float4*)&As[kk][ty << 2];
            float4 bv = *(const float4*)&Bs[kk][tx << 2];
            acc[0][0] = fmaf(av.x, bv.x, acc[0][0]);
            acc[0][1] = fmaf(av.x, bv.y, acc[0][1]);
            acc[0][2] = fmaf(av.x, bv.z, acc[0][2]);
            acc[0][3] = fmaf(av.x, bv.w, acc[0][3]);
            acc[1][0] = fmaf(av.y, bv.x, acc[1][0]);
            acc[1][1] = fmaf(av.y, bv.y, acc[1][1]);
            acc[1][2] = fmaf(av.y, bv.z, acc[1][2]);
            acc[1][3] = fmaf(av.y, bv.w, acc[1][3]);
            acc[2][0] = fmaf(av.z, bv.x, acc[2][0]);
            acc[2][1] = fmaf(av.z, bv.y, acc[2][1]);
            acc[2][2] = fmaf(av.z, bv.z, acc[2][2]);
            acc[2][3] = fmaf(av.z, bv.w, acc[2][3]);
            acc[3][0] = fmaf(av.w, bv.x, acc[3][0]);
            acc[3][1] = fmaf(av.w, bv.y, acc[3][1]);
            acc[3][2] = fmaf(av.w, bv.z, acc[3][2]);
            acc[3][3] = fmaf(av.w, bv.w, acc[3][3]);
        }
    }
    const int row0 = by*64 + (ty << 2), col0 = bx*64 + (tx << 2);
    float4 bb = *(const float4*)(bias + col0);
    #pragma unroll
    for (int i = 0; i < 4; ++i) {
        float4 o;
        o.x = acc[i][0] + bb.x; o.y = acc[i][1] + bb.y;
        o.z = acc[i][2] + bb.z; o.w = acc[i][3] + bb.w;
        if (relu) {
            o.x = fmaxf(o.x, 0.f); o.y = fmaxf(o.y, 0.f);
            o.z = fmaxf(o.z, 0.f); o.w = fmaxf(o.w, 0.f);
        }
        *(float4*)(C + (size_t)(row0 + i)*N + col0) = o;
    }
}

// ---------------------------------------------------------------------------
// Input-population LIF -> spike bitmasks. masks layout: [b][s*T+t][wq] u64 x16
// ---------------------------------------------------------------------------
__global__ __launch_bounds__(256) void k_lif_in(const float* __restrict__ snn,
                                                unsigned long long* __restrict__ masks,
                                                unsigned int* __restrict__ counters)
{
    const int tid  = blockIdx.x * 256 + threadIdx.x;
    const int w    = tid >> 6;
    const int lane = tid & 63;
    const int b    = w >> 4;
    const int nb   = w & 15;
    const int n    = (nb << 6) + lane;
    float v = 0.f;
    int cnt = 0;
    const float* cur = snn + (size_t)(b * S) * NIN + n;
    unsigned long long* mrow = masks + (size_t)(b * (S*T)) * 16 + nb;
    for (int s = 0; s < S; ++s) {
        const float I = cur[(size_t)s * NIN];
        #pragma unroll
        for (int t = 0; t < T; ++t) {
            v = __fadd_rn(__fmul_rn(0.9f, v), I);
            const bool sp = (v >= 1.0f);
            const unsigned long long m = __ballot(sp);
            v = sp ? (v - 1.0f) : v;
            cnt += sp ? 1 : 0;
            if (lane == 0) mrow[(size_t)(s*T + t) * 16] = m;
        }
    }
    atomicAdd(counters, (unsigned int)cnt);
}

// ---------------------------------------------------------------------------
// Prep: transpose W_conn [k][n] -> WcT [n][k] and split fp32 = bf16_hi+bf16_lo
// ---------------------------------------------------------------------------
__global__ __launch_bounds__(256) void k_prep(const float* __restrict__ Wc,
                                              unsigned short* __restrict__ WhT,
                                              unsigned short* __restrict__ WlT)
{
    __shared__ float tile[64][65];
    const int k0 = blockIdx.x * 64, n0 = blockIdx.y * 64;
    const int tx = threadIdx.x & 63, ty = threadIdx.x >> 6;
    #pragma unroll
    for (int p = 0; p < 16; ++p) {
        const int kl = p*4 + ty;
        tile[kl][tx] = Wc[(size_t)(k0 + kl) * NOUT + n0 + tx];
    }
    __syncthreads();
    #pragma unroll
    for (int p = 0; p < 16; ++p) {
        const int nl = p*4 + ty;
        const float w = tile[tx][nl];
        const unsigned int u  = __float_as_uint(w);
        const unsigned int hb = (u + 0x7FFFu + ((u >> 16) & 1u)) & 0xFFFF0000u; // bf16 RNE
        const float hif = __uint_as_float(hb);
        const float lo  = w - hif;                                             // exact
        const unsigned int ul = __float_as_uint(lo);
        const unsigned short lob = (unsigned short)((ul + 0x7FFFu + ((ul >> 16) & 1u)) >> 16);
        WhT[(size_t)(n0 + nl) * NIN + k0 + tx] = (unsigned short)(hb >> 16);
        WlT[(size_t)(n0 + nl) * NIN + k0 + tx] = lob;
    }
}

// ---------------------------------------------------------------------------
// Spike GEMM via MFMA: Iout[M=B*P*T rows][1024] = Sbits @ (Whi + Wlo).
// Block tile 256x64, 4 waves (each 64 rows x 64 cols, 4x4 16x16 frags).
// A-frags decoded from bitmasks via 256-entry LDS LUT (byte -> 8 bf16 0/1).
// ---------------------------------------------------------------------------
__global__ __launch_bounds__(256) void k_conn_mfma(const uint4* __restrict__ masks128,
                                                   const unsigned short* __restrict__ WhT,
                                                   const unsigned short* __restrict__ WlT,
                                                   float* __restrict__ Iout,
                                                   int s0, int P)
{
    __shared__ uint4 lut[256];
    const int tid = threadIdx.x;
    {
        const unsigned int bb = (unsigned int)tid;
        unsigned int r[4];
        #pragma unroll
        for (int i = 0; i < 4; ++i) {
            const unsigned int b0 = (bb >> (2*i)) & 1u, b1 = (bb >> (2*i+1)) & 1u;
            r[i] = (b0 ? 0x3F80u : 0u) | (b1 ? 0x3F800000u : 0u);
        }
        lut[tid] = make_uint4(r[0], r[1], r[2], r[3]);
    }
    __syncthreads();

    const int w = tid >> 6, lane = tid & 63;
    const int r16 = lane & 15, q = lane >> 4;
    const int PT = P * T;
    const int rowblk = blockIdx.x * 256 + w * 64;
    const int cb = blockIdx.y * 64;

    // A mask row pointers (8 x uint4 per 1024-bit row)
    const uint4* aptr[4];
    #pragma unroll
    for (int f = 0; f < 4; ++f) {
        const int r = rowblk + f*16 + r16;
        const int b = r / PT;
        const int within = r - b * PT;
        const int grow = (b * S + s0) * T + within;
        aptr[f] = masks128 + (size_t)grow * 8;
    }
    const unsigned short* bhp = WhT + (size_t)(cb + r16) * NIN + q * 8;
    const unsigned short* blp = WlT + (size_t)(cb + r16) * NIN + q * 8;

    floatx4 acc[4][4];
    #pragma unroll
    for (int f = 0; f < 4; ++f)
        #pragma unroll
        for (int c = 0; c < 4; ++c)
            acc[f][c] = (floatx4){0.f, 0.f, 0.f, 0.f};

    for (int kc4 = 0; kc4 < 8; ++kc4) {
        uint4 aw[4];
        #pragma unroll
        for (int f = 0; f < 4; ++f) aw[f] = aptr[f][kc4];
        #pragma unroll
        for (int u = 0; u < 4; ++u) {
            const int kc = kc4*4 + u;
            short8 bh[4], bl[4];
            #pragma unroll
            for (int c = 0; c < 4; ++c) {
                bh[c] = *(const short8*)(bhp + (size_t)c*16*NIN + kc*32);
                bl[c] = *(const short8*)(blp + (size_t)c*16*NIN + kc*32);
            }
            #pragma unroll
            for (int f = 0; f < 4; ++f) {
                const unsigned int word = (u == 0) ? aw[f].x : (u == 1) ? aw[f].y
                                         : (u == 2) ? aw[f].z : aw[f].w;
                const unsigned int byte = (word >> (q * 8)) & 0xFFu;
                const short8 a = *(const short8*)&lut[byte];
                #pragma unroll
                for (int c = 0; c < 4; ++c) {
                    acc[f][c] = __builtin_amdgcn_mfma_f32_16x16x32_bf16(a, bh[c], acc[f][c], 0, 0, 0);
                    acc[f][c] = __builtin_amdgcn_mfma_f32_16x16x32_bf16(a, bl[c], acc[f][c], 0, 0, 0);
                }
            }
        }
    }

    // epilogue: C/D layout col=lane&15, row=(lane>>4)*4+reg
    #pragma unroll
    for (int f = 0; f < 4; ++f) {
        const int row = rowblk + f*16 + q*4;
        #pragma unroll
        for (int c = 0; c < 4; ++c) {
            const int col = cb + c*16 + r16;
            #pragma unroll
            for (int i = 0; i < 4; ++i)
                Iout[(size_t)(row + i) * NOUT + col] = acc[f][c][i];
        }
    }
}

// ---------------------------------------------------------------------------
// Output-population LIF
// ---------------------------------------------------------------------------
__global__ __launch_bounds__(256) void k_lif_out(const float* __restrict__ Iout,
                                                 float* __restrict__ vstate,
                                                 float* __restrict__ sacc_out,
                                                 unsigned int* __restrict__ counters,
                                                 int s0, int P, int init)
{
    const int tid = blockIdx.x * 256 + threadIdx.x;
    const int b = tid >> 10, n = tid & (NOUT - 1);
    const int Tc = P * T;
    float v = init ? 0.f : vstate[tid];
    const float* ip = Iout + (size_t)b * Tc * NOUT + n;
    int cnt = 0;
    for (int sl = 0; sl < P; ++sl) {
        float sacc = 0.f;
        #pragma unroll
        for (int t = 0; t < T; ++t) {
            const float I = ip[(size_t)(sl*T + t) * NOUT];
            v = __fadd_rn(__fmul_rn(0.9f, v), I);
            const bool sp = (v >= 1.0f);
            v = sp ? (v - 1.0f) : v;
            sacc += sp ? 1.f : 0.f;
            cnt += sp ? 1 : 0;
        }
        sacc_out[(size_t)(b*S + s0 + sl) * NOUT + n] = sacc;
    }
    vstate[tid] = v;
    atomicAdd(counters + 1, (unsigned int)cnt);
}

__global__ void k_init(unsigned int* c)
{
    if (threadIdx.x < 2) c[threadIdx.x] = 0u;
}

__global__ void k_rate(const unsigned int* __restrict__ c, float* __restrict__ out)
{
    if (threadIdx.x == 0 && blockIdx.x == 0) {
        const float total = (float)c[0] + (float)c[1];
        out[0] = total / (float)(B * S * (NIN + NOUT) * T);
    }
}

// ---------------------------------------------------------------------------
extern "C" void kernel_launch(void* const* d_in, const int* in_sizes, int n_in,
                              void* d_out, int out_size, void* d_ws, size_t ws_size,
                              hipStream_t stream)
{
    const float* E    = (const float*)d_in[0];
    const float* Win  = (const float*)d_in[1];
    const float* bin  = (const float*)d_in[2];
    const float* Wc   = (const float*)d_in[3];
    const float* Wout = (const float*)d_in[4];
    const float* bout = (const float*)d_in[5];
    float* out = (float*)d_out;

    char* w = (char*)d_ws;
    float* snn              = (float*)(w);                          // 4 MB (later reused for WcT)
    unsigned short* WhT     = (unsigned short*)(w);                 // 2 MB (aliases snn, after lif_in)
    unsigned short* WlT     = (unsigned short*)(w + (2 << 20));     // 2 MB
    unsigned long long* msk = (unsigned long long*)(w + (4 << 20)); // 4 MB
    float* sacc             = (float*)(w + (8 << 20));              // 4 MB
    float* vst              = (float*)(w + (12 << 20));             // 32 KB
    unsigned int* cnt       = (unsigned int*)(w + (12 << 20) + (64 << 10));
    float* Iout             = (float*)(w + (13 << 20));

    const size_t base = (size_t)13 << 20;
    const size_t avail = (ws_size > base) ? (ws_size - base) : 0;
    int P = 1;
    if      (avail >= (size_t)B * 128 * T * NOUT * 4) P = 128;
    else if (avail >= (size_t)B *  16 * T * NOUT * 4) P = 16;
    else if (avail >= (size_t)B *   4 * T * NOUT * 4) P = 4;

    k_init<<<1, 64, 0, stream>>>(cnt);

    dim3 g1(NIN / 64, (B * S) / 64);
    k_gemm<<<g1, 256, 0, stream>>>(E, Win, bin, snn, B * S, NIN, D, 1);

    k_lif_in<<<32, 256, 0, stream>>>(snn, msk, cnt);

    // snn is dead now: build transposed hi/lo bf16 split of W_conn in its place
    dim3 gp(NIN / 64, NOUT / 64);
    k_prep<<<gp, 256, 0, stream>>>(Wc, WhT, WlT);

    for (int c = 0; c < S / P; ++c) {
        dim3 gc((B * P * T) / 256, NOUT / 64);
        k_conn_mfma<<<gc, 256, 0, stream>>>((const uint4*)msk, WhT, WlT, Iout, c * P, P);
        k_lif_out<<<32, 256, 0, stream>>>(Iout, vst, sacc, cnt, c * P, P, c == 0 ? 1 : 0);
    }

    dim3 g2(D / 64, (B * S) / 64);
    k_gemm<<<g2, 256, 0, stream>>>(sacc, Wout, bout, out, B * S, D, NOUT, 0);

    k_rate<<<1, 64, 0, stream>>>(cnt, out + (size_t)B * S * D);
}

// Round 4
// 575.418 us; speedup vs baseline: 4.3874x; 1.2550x over previous
//
#include <hip/hip_runtime.h>
#include <stdint.h>

#define B 8
#define S 128
#define D 512
#define NIN 1024
#define NOUT 1024
#define T 32

typedef __attribute__((ext_vector_type(8))) short short8;
typedef __attribute__((ext_vector_type(4))) float floatx4;

// ---------------------------------------------------------------------------
// Generic fp32 tiled GEMM: C[M,N] = maybe_relu(A[M,K] @ Bm[K,N] + bias[N])
// ---------------------------------------------------------------------------
__global__ __launch_bounds__(256) void k_gemm(const float* __restrict__ A,
                                              const float* __restrict__ Bm,
                                              const float* __restrict__ bias,
                                              float* __restrict__ C,
                                              int M, int N, int K, int relu)
{
    __shared__ float As[16][64];
    __shared__ float Bs[16][64];
    const int tid = threadIdx.x;
    const int bx = blockIdx.x, by = blockIdx.y;
    const int tx = tid & 15, ty = tid >> 4;
    const int ar = tid >> 2, ak = (tid & 3) << 2;
    const int bk = tid >> 4, bc = (tid & 15) << 2;
    float acc[4][4] = {{0.f,0.f,0.f,0.f},{0.f,0.f,0.f,0.f},
                       {0.f,0.f,0.f,0.f},{0.f,0.f,0.f,0.f}};
    for (int k0 = 0; k0 < K; k0 += 16) {
        float4 a4 = *(const float4*)(A + (size_t)(by*64 + ar)*K + k0 + ak);
        float4 b4 = *(const float4*)(Bm + (size_t)(k0 + bk)*N + bx*64 + bc);
        __syncthreads();
        As[ak+0][ar] = a4.x; As[ak+1][ar] = a4.y;
        As[ak+2][ar] = a4.z; As[ak+3][ar] = a4.w;
        *(float4*)&Bs[bk][bc] = b4;
        __syncthreads();
        #pragma unroll
        for (int kk = 0; kk < 16; ++kk) {
            float4 av = *(const float4*)&As[kk][ty << 2];
            float4 bv = *(const float4*)&Bs[kk][tx << 2];
            acc[0][0] = fmaf(av.x, bv.x, acc[0][0]);
            acc[0][1] = fmaf(av.x, bv.y, acc[0][1]);
            acc[0][2] = fmaf(av.x, bv.z, acc[0][2]);
            acc[0][3] = fmaf(av.x, bv.w, acc[0][3]);
            acc[1][0] = fmaf(av.y, bv.x, acc[1][0]);
            acc[1][1] = fmaf(av.y, bv.y, acc[1][1]);
            acc[1][2] = fmaf(av.y, bv.z, acc[1][2]);
            acc[1][3] = fmaf(av.y, bv.w, acc[1][3]);
            acc[2][0] = fmaf(av.z, bv.x, acc[2][0]);
            acc[2][1] = fmaf(av.z, bv.y, acc[2][1]);
            acc[2][2] = fmaf(av.z, bv.z, acc[2][2]);
            acc[2][3] = fmaf(av.z, bv.w, acc[2][3]);
            acc[3][0] = fmaf(av.w, bv.x, acc[3][0]);
            acc[3][1] = fmaf(av.w, bv.y, acc[3][1]);
            acc[3][2] = fmaf(av.w, bv.z, acc[3][2]);
            acc[3][3] = fmaf(av.w, bv.w, acc[3][3]);
        }
    }
    const int row0 = by*64 + (ty << 2), col0 = bx*64 + (tx << 2);
    float4 bb = *(const float4*)(bias + col0);
    #pragma unroll
    for (int i = 0; i < 4; ++i) {
        float4 o;
        o.x = acc[i][0] + bb.x; o.y = acc[i][1] + bb.y;
        o.z = acc[i][2] + bb.z; o.w = acc[i][3] + bb.w;
        if (relu) {
            o.x = fmaxf(o.x, 0.f); o.y = fmaxf(o.y, 0.f);
            o.z = fmaxf(o.z, 0.f); o.w = fmaxf(o.w, 0.f);
        }
        *(float4*)(C + (size_t)(row0 + i)*N + col0) = o;
    }
}

// ---------------------------------------------------------------------------
// Input-population LIF -> spike bitmasks. masks layout: [b][s*T+t][wq] u64 x16
// ---------------------------------------------------------------------------
__global__ __launch_bounds__(256) void k_lif_in(const float* __restrict__ snn,
                                                unsigned long long* __restrict__ masks,
                                                unsigned int* __restrict__ counters)
{
    const int tid  = blockIdx.x * 256 + threadIdx.x;
    const int w    = tid >> 6;
    const int lane = tid & 63;
    const int b    = w >> 4;
    const int nb   = w & 15;
    const int n    = (nb << 6) + lane;
    float v = 0.f;
    int cnt = 0;
    const float* cur = snn + (size_t)(b * S) * NIN + n;
    unsigned long long* mrow = masks + (size_t)(b * (S*T)) * 16 + nb;
    for (int s = 0; s < S; ++s) {
        const float I = cur[(size_t)s * NIN];
        #pragma unroll
        for (int t = 0; t < T; ++t) {
            v = __fadd_rn(__fmul_rn(0.9f, v), I);
            const bool sp = (v >= 1.0f);
            const unsigned long long m = __ballot(sp);
            v = sp ? (v - 1.0f) : v;
            cnt += sp ? 1 : 0;
            if (lane == 0) mrow[(size_t)(s*T + t) * 16] = m;
        }
    }
    atomicAdd(counters, (unsigned int)cnt);
}

// ---------------------------------------------------------------------------
// Prep: transpose W_conn [k][n] -> WcT [n][k] and split fp32 = bf16_hi+bf16_lo
// ---------------------------------------------------------------------------
__global__ __launch_bounds__(256) void k_prep(const float* __restrict__ Wc,
                                              unsigned short* __restrict__ WhT,
                                              unsigned short* __restrict__ WlT)
{
    __shared__ float tile[64][65];
    const int k0 = blockIdx.x * 64, n0 = blockIdx.y * 64;
    const int tx = threadIdx.x & 63, ty = threadIdx.x >> 6;
    #pragma unroll
    for (int p = 0; p < 16; ++p) {
        const int kl = p*4 + ty;
        tile[kl][tx] = Wc[(size_t)(k0 + kl) * NOUT + n0 + tx];
    }
    __syncthreads();
    #pragma unroll
    for (int p = 0; p < 16; ++p) {
        const int nl = p*4 + ty;
        const float w = tile[tx][nl];
        const unsigned int u  = __float_as_uint(w);
        const unsigned int hb = (u + 0x7FFFu + ((u >> 16) & 1u)) & 0xFFFF0000u; // bf16 RNE
        const float hif = __uint_as_float(hb);
        const float lo  = w - hif;                                             // exact
        const unsigned int ul = __float_as_uint(lo);
        const unsigned short lob = (unsigned short)((ul + 0x7FFFu + ((ul >> 16) & 1u)) >> 16);
        WhT[(size_t)(n0 + nl) * NIN + k0 + tx] = (unsigned short)(hb >> 16);
        WlT[(size_t)(n0 + nl) * NIN + k0 + tx] = lob;
    }
}

// ---------------------------------------------------------------------------
// Spike GEMM via MFMA: Iout[M=B*P*T rows][1024] = Sbits @ (Whi + Wlo).
// Block tile 256x64, 4 waves (each 64 rows x 64 cols, 4x4 16x16 frags).
// B hi/lo K-chunks (128 k) staged in LDS, shared across all 4 waves
// (fixes R3's 4x-redundant L2 reads). Col stride padded to 136 shorts so
// 16-lane frag reads spread banks. A-frags decoded from bitmasks via LDS LUT.
// MFMA accumulation order identical to R3 -> bitwise-identical Iout.
// ---------------------------------------------------------------------------
__global__ __launch_bounds__(256) void k_conn_mfma(const uint4* __restrict__ masks128,
                                                   const unsigned short* __restrict__ WhT,
                                                   const unsigned short* __restrict__ WlT,
                                                   float* __restrict__ Iout,
                                                   int s0, int P)
{
    __shared__ uint4 lut[256];
    __shared__ unsigned short Bsm[2][64][136];   // [mat][col][k] padded +8

    const int tid = threadIdx.x;
    {
        const unsigned int bb = (unsigned int)tid;
        unsigned int r[4];
        #pragma unroll
        for (int i = 0; i < 4; ++i) {
            const unsigned int b0 = (bb >> (2*i)) & 1u, b1 = (bb >> (2*i+1)) & 1u;
            r[i] = (b0 ? 0x3F80u : 0u) | (b1 ? 0x3F800000u : 0u);
        }
        lut[tid] = make_uint4(r[0], r[1], r[2], r[3]);
    }

    const int w = tid >> 6, lane = tid & 63;
    const int r16 = lane & 15, q = lane >> 4;
    const int PT = P * T;
    const int rowblk = blockIdx.x * 256 + w * 64;
    const int cb = blockIdx.y * 64;

    // A mask row pointers (8 x uint4 per 1024-bit row)
    const uint4* aptr[4];
    #pragma unroll
    for (int f = 0; f < 4; ++f) {
        const int r = rowblk + f*16 + r16;
        const int b = r / PT;
        const int within = r - b * PT;
        const int grow = (b * S + s0) * T + within;
        aptr[f] = masks128 + (size_t)grow * 8;
    }

    // staging indices (8 x 16B per thread per chunk)
    const int sflat0 = tid;            // + i*256, i=0..7 -> 0..2047
    floatx4 acc[4][4];
    #pragma unroll
    for (int f = 0; f < 4; ++f)
        #pragma unroll
        for (int c = 0; c < 4; ++c)
            acc[f][c] = (floatx4){0.f, 0.f, 0.f, 0.f};

    for (int ch = 0; ch < 8; ++ch) {
        __syncthreads();   // previous chunk's reads done (also covers LUT init)
        #pragma unroll
        for (int i = 0; i < 8; ++i) {
            const int flat = sflat0 + i * 256;      // [mat(1)|col(6)|k16(4)]
            const int mat  = flat >> 10;
            const int rest = flat & 1023;
            const int col  = rest >> 4;
            const int k16  = rest & 15;
            const unsigned short* src =
                (mat ? WlT : WhT) + (size_t)(cb + col) * NIN + ch * 128 + k16 * 8;
            *(uint4*)&Bsm[mat][col][k16 * 8] = *(const uint4*)src;
        }
        uint4 aw[4];
        #pragma unroll
        for (int f = 0; f < 4; ++f) aw[f] = aptr[f][ch];
        __syncthreads();

        #pragma unroll
        for (int kc = 0; kc < 4; ++kc) {
            short8 bh[4], bl[4];
            #pragma unroll
            for (int c = 0; c < 4; ++c) {
                bh[c] = *(const short8*)&Bsm[0][c*16 + r16][kc*32 + q*8];
                bl[c] = *(const short8*)&Bsm[1][c*16 + r16][kc*32 + q*8];
            }
            #pragma unroll
            for (int f = 0; f < 4; ++f) {
                const unsigned int word = (kc == 0) ? aw[f].x : (kc == 1) ? aw[f].y
                                         : (kc == 2) ? aw[f].z : aw[f].w;
                const unsigned int byte = (word >> (q * 8)) & 0xFFu;
                const short8 a = *(const short8*)&lut[byte];
                #pragma unroll
                for (int c = 0; c < 4; ++c) {
                    acc[f][c] = __builtin_amdgcn_mfma_f32_16x16x32_bf16(a, bh[c], acc[f][c], 0, 0, 0);
                    acc[f][c] = __builtin_amdgcn_mfma_f32_16x16x32_bf16(a, bl[c], acc[f][c], 0, 0, 0);
                }
            }
        }
    }

    // epilogue: C/D layout col=lane&15, row=(lane>>4)*4+reg
    #pragma unroll
    for (int f = 0; f < 4; ++f) {
        const int row = rowblk + f*16 + q*4;
        #pragma unroll
        for (int c = 0; c < 4; ++c) {
            const int col = cb + c*16 + r16;
            #pragma unroll
            for (int i = 0; i < 4; ++i)
                Iout[(size_t)(row + i) * NOUT + col] = acc[f][c][i];
        }
    }
}

// ---------------------------------------------------------------------------
// Output-population LIF
// ---------------------------------------------------------------------------
__global__ __launch_bounds__(256) void k_lif_out(const float* __restrict__ Iout,
                                                 float* __restrict__ vstate,
                                                 float* __restrict__ sacc_out,
                                                 unsigned int* __restrict__ counters,
                                                 int s0, int P, int init)
{
    const int tid = blockIdx.x * 256 + threadIdx.x;
    const int b = tid >> 10, n = tid & (NOUT - 1);
    const int Tc = P * T;
    float v = init ? 0.f : vstate[tid];
    const float* ip = Iout + (size_t)b * Tc * NOUT + n;
    int cnt = 0;
    for (int sl = 0; sl < P; ++sl) {
        float sacc = 0.f;
        #pragma unroll
        for (int t = 0; t < T; ++t) {
            const float I = ip[(size_t)(sl*T + t) * NOUT];
            v = __fadd_rn(__fmul_rn(0.9f, v), I);
            const bool sp = (v >= 1.0f);
            v = sp ? (v - 1.0f) : v;
            sacc += sp ? 1.f : 0.f;
            cnt += sp ? 1 : 0;
        }
        sacc_out[(size_t)(b*S + s0 + sl) * NOUT + n] = sacc;
    }
    vstate[tid] = v;
    atomicAdd(counters + 1, (unsigned int)cnt);
}

__global__ void k_init(unsigned int* c)
{
    if (threadIdx.x < 2) c[threadIdx.x] = 0u;
}

__global__ void k_rate(const unsigned int* __restrict__ c, float* __restrict__ out)
{
    if (threadIdx.x == 0 && blockIdx.x == 0) {
        const float total = (float)c[0] + (float)c[1];
        out[0] = total / (float)(B * S * (NIN + NOUT) * T);
    }
}

// ---------------------------------------------------------------------------
extern "C" void kernel_launch(void* const* d_in, const int* in_sizes, int n_in,
                              void* d_out, int out_size, void* d_ws, size_t ws_size,
                              hipStream_t stream)
{
    const float* E    = (const float*)d_in[0];
    const float* Win  = (const float*)d_in[1];
    const float* bin  = (const float*)d_in[2];
    const float* Wc   = (const float*)d_in[3];
    const float* Wout = (const float*)d_in[4];
    const float* bout = (const float*)d_in[5];
    float* out = (float*)d_out;

    char* w = (char*)d_ws;
    float* snn              = (float*)(w);                          // 4 MB (later reused for WcT)
    unsigned short* WhT     = (unsigned short*)(w);                 // 2 MB (aliases snn, after lif_in)
    unsigned short* WlT     = (unsigned short*)(w + (2 << 20));     // 2 MB
    unsigned long long* msk = (unsigned long long*)(w + (4 << 20)); // 4 MB
    float* sacc             = (float*)(w + (8 << 20));              // 4 MB
    float* vst              = (float*)(w + (12 << 20));             // 32 KB
    unsigned int* cnt       = (unsigned int*)(w + (12 << 20) + (64 << 10));
    float* Iout             = (float*)(w + (13 << 20));

    const size_t base = (size_t)13 << 20;
    const size_t avail = (ws_size > base) ? (ws_size - base) : 0;
    int P = 1;
    if      (avail >= (size_t)B * 128 * T * NOUT * 4) P = 128;
    else if (avail >= (size_t)B *  16 * T * NOUT * 4) P = 16;
    else if (avail >= (size_t)B *   4 * T * NOUT * 4) P = 4;

    k_init<<<1, 64, 0, stream>>>(cnt);

    dim3 g1(NIN / 64, (B * S) / 64);
    k_gemm<<<g1, 256, 0, stream>>>(E, Win, bin, snn, B * S, NIN, D, 1);

    k_lif_in<<<32, 256, 0, stream>>>(snn, msk, cnt);

    // snn is dead now: build transposed hi/lo bf16 split of W_conn in its place
    dim3 gp(NIN / 64, NOUT / 64);
    k_prep<<<gp, 256, 0, stream>>>(Wc, WhT, WlT);

    for (int c = 0; c < S / P; ++c) {
        dim3 gc((B * P * T) / 256, NOUT / 64);
        k_conn_mfma<<<gc, 256, 0, stream>>>((const uint4*)msk, WhT, WlT, Iout, c * P, P);
        k_lif_out<<<32, 256, 0, stream>>>(Iout, vst, sacc, cnt, c * P, P, c == 0 ? 1 : 0);
    }

    dim3 g2(D / 64, (B * S) / 64);
    k_gemm<<<g2, 256, 0, stream>>>(sacc, Wout, bout, out, B * S, D, NOUT, 0);

    k_rate<<<1, 64, 0, stream>>>(cnt, out + (size_t)B * S * D);
}

// Round 5
// 473.448 us; speedup vs baseline: 5.3324x; 1.2154x over previous
//
#include <hip/hip_runtime.h>
#include <stdint.h>

#define B 8
#define S 128
#define D 512
#define NIN 1024
#define NOUT 1024
#define T 32

typedef __attribute__((ext_vector_type(8))) short short8;
typedef __attribute__((ext_vector_type(4))) float floatx4;

// ---------------------------------------------------------------------------
// Generic fp32 tiled GEMM: C[M,N] = maybe_relu(A[M,K] @ Bm[K,N] + bias[N])
// ---------------------------------------------------------------------------
__global__ __launch_bounds__(256) void k_gemm(const float* __restrict__ A,
                                              const float* __restrict__ Bm,
                                              const float* __restrict__ bias,
                                              float* __restrict__ C,
                                              int M, int N, int K, int relu)
{
    __shared__ float As[16][64];
    __shared__ float Bs[16][64];
    const int tid = threadIdx.x;
    const int bx = blockIdx.x, by = blockIdx.y;
    const int tx = tid & 15, ty = tid >> 4;
    const int ar = tid >> 2, ak = (tid & 3) << 2;
    const int bk = tid >> 4, bc = (tid & 15) << 2;
    float acc[4][4] = {{0.f,0.f,0.f,0.f},{0.f,0.f,0.f,0.f},
                       {0.f,0.f,0.f,0.f},{0.f,0.f,0.f,0.f}};
    for (int k0 = 0; k0 < K; k0 += 16) {
        float4 a4 = *(const float4*)(A + (size_t)(by*64 + ar)*K + k0 + ak);
        float4 b4 = *(const float4*)(Bm + (size_t)(k0 + bk)*N + bx*64 + bc);
        __syncthreads();
        As[ak+0][ar] = a4.x; As[ak+1][ar] = a4.y;
        As[ak+2][ar] = a4.z; As[ak+3][ar] = a4.w;
        *(float4*)&Bs[bk][bc] = b4;
        __syncthreads();
        #pragma unroll
        for (int kk = 0; kk < 16; ++kk) {
            float4 av = *(const float4*)&As[kk][ty << 2];
            float4 bv = *(const float4*)&Bs[kk][tx << 2];
            acc[0][0] = fmaf(av.x, bv.x, acc[0][0]);
            acc[0][1] = fmaf(av.x, bv.y, acc[0][1]);
            acc[0][2] = fmaf(av.x, bv.z, acc[0][2]);
            acc[0][3] = fmaf(av.x, bv.w, acc[0][3]);
            acc[1][0] = fmaf(av.y, bv.x, acc[1][0]);
            acc[1][1] = fmaf(av.y, bv.y, acc[1][1]);
            acc[1][2] = fmaf(av.y, bv.z, acc[1][2]);
            acc[1][3] = fmaf(av.y, bv.w, acc[1][3]);
            acc[2][0] = fmaf(av.z, bv.x, acc[2][0]);
            acc[2][1] = fmaf(av.z, bv.y, acc[2][1]);
            acc[2][2] = fmaf(av.z, bv.z, acc[2][2]);
            acc[2][3] = fmaf(av.z, bv.w, acc[2][3]);
            acc[3][0] = fmaf(av.w, bv.x, acc[3][0]);
            acc[3][1] = fmaf(av.w, bv.y, acc[3][1]);
            acc[3][2] = fmaf(av.w, bv.z, acc[3][2]);
            acc[3][3] = fmaf(av.w, bv.w, acc[3][3]);
        }
    }
    const int row0 = by*64 + (ty << 2), col0 = bx*64 + (tx << 2);
    float4 bb = *(const float4*)(bias + col0);
    #pragma unroll
    for (int i = 0; i < 4; ++i) {
        float4 o;
        o.x = acc[i][0] + bb.x; o.y = acc[i][1] + bb.y;
        o.z = acc[i][2] + bb.z; o.w = acc[i][3] + bb.w;
        if (relu) {
            o.x = fmaxf(o.x, 0.f); o.y = fmaxf(o.y, 0.f);
            o.z = fmaxf(o.z, 0.f); o.w = fmaxf(o.w, 0.f);
        }
        *(float4*)(C + (size_t)(row0 + i)*N + col0) = o;
    }
}

// ---------------------------------------------------------------------------
// Input LIF phase A: bare serial chain only. One thread per (b, n_in).
// Spike bits for 32 timesteps pack into a u32 (off the dependency chain);
// one coalesced u32 store per position; I prefetched one position ahead.
// Arithmetic identical to previous rounds -> bit-identical spikes.
// sbits layout: [b*S+s][n] u32 (bit = t)
// ---------------------------------------------------------------------------
__global__ __launch_bounds__(256) void k_lif_inA(const float* __restrict__ snn,
                                                 unsigned int* __restrict__ sbits,
                                                 unsigned int* __restrict__ counters)
{
    const int tid = blockIdx.x * 256 + threadIdx.x;   // 0..8191
    const int b = tid >> 10, n = tid & (NIN - 1);
    const float* cur = snn + (size_t)(b * S) * NIN + n;
    float v = 0.f;
    int cnt = 0;
    float I = cur[0];
    for (int s = 0; s < S; ++s) {
        const float In = (s + 1 < S) ? cur[(size_t)(s + 1) * NIN] : 0.f;
        unsigned int bits = 0u;
        #pragma unroll
        for (int t = 0; t < T; ++t) {
            v = __fadd_rn(__fmul_rn(0.9f, v), I);
            const bool sp = (v >= 1.0f);
            v = sp ? (v - 1.0f) : v;
            bits |= (sp ? 1u : 0u) << t;
        }
        sbits[(size_t)(b * S + s) * NIN + n] = bits;
        cnt += __popc(bits);
        I = In;
    }
    atomicAdd(counters, (unsigned int)cnt);
}

// ---------------------------------------------------------------------------
// Input LIF phase B: parallel rebuild of the u64 ballot masks consumed by
// k_conn_mfma. Block = one (b,s); wave w handles wq = w*4..w*4+3.
// masks layout: [(b*S+s)*T + t][wq] u64 (bit = lane = n - wq*64) — identical
// to the old k_lif_in output.
// ---------------------------------------------------------------------------
__global__ __launch_bounds__(256) void k_lif_inB(const unsigned int* __restrict__ sbits,
                                                 unsigned long long* __restrict__ masks)
{
    const int bs = blockIdx.x;                 // b*S+s
    const int w = threadIdx.x >> 6, lane = threadIdx.x & 63;
    #pragma unroll
    for (int i = 0; i < 4; ++i) {
        const int wq = w * 4 + i;
        const unsigned int bits = sbits[(size_t)bs * NIN + wq * 64 + lane];
        #pragma unroll
        for (int t = 0; t < T; ++t) {
            const unsigned long long m = __ballot((bits >> t) & 1u);
            if (lane == 0)
                masks[((size_t)bs * T + t) * 16 + wq] = m;
        }
    }
}

// ---------------------------------------------------------------------------
// Prep: transpose W_conn [k][n] -> WcT [n][k] and split fp32 = bf16_hi+bf16_lo
// ---------------------------------------------------------------------------
__global__ __launch_bounds__(256) void k_prep(const float* __restrict__ Wc,
                                              unsigned short* __restrict__ WhT,
                                              unsigned short* __restrict__ WlT)
{
    __shared__ float tile[64][65];
    const int k0 = blockIdx.x * 64, n0 = blockIdx.y * 64;
    const int tx = threadIdx.x & 63, ty = threadIdx.x >> 6;
    #pragma unroll
    for (int p = 0; p < 16; ++p) {
        const int kl = p*4 + ty;
        tile[kl][tx] = Wc[(size_t)(k0 + kl) * NOUT + n0 + tx];
    }
    __syncthreads();
    #pragma unroll
    for (int p = 0; p < 16; ++p) {
        const int nl = p*4 + ty;
        const float w = tile[tx][nl];
        const unsigned int u  = __float_as_uint(w);
        const unsigned int hb = (u + 0x7FFFu + ((u >> 16) & 1u)) & 0xFFFF0000u; // bf16 RNE
        const float hif = __uint_as_float(hb);
        const float lo  = w - hif;                                             // exact
        const unsigned int ul = __float_as_uint(lo);
        const unsigned short lob = (unsigned short)((ul + 0x7FFFu + ((ul >> 16) & 1u)) >> 16);
        WhT[(size_t)(n0 + nl) * NIN + k0 + tx] = (unsigned short)(hb >> 16);
        WlT[(size_t)(n0 + nl) * NIN + k0 + tx] = lob;
    }
}

// ---------------------------------------------------------------------------
// Spike GEMM via MFMA (unchanged from R4): Iout = Sbits @ (Whi + Wlo),
// B staged in LDS shared by 4 waves, A decoded from bitmasks via LDS LUT.
// ---------------------------------------------------------------------------
__global__ __launch_bounds__(256) void k_conn_mfma(const uint4* __restrict__ masks128,
                                                   const unsigned short* __restrict__ WhT,
                                                   const unsigned short* __restrict__ WlT,
                                                   float* __restrict__ Iout,
                                                   int s0, int P)
{
    __shared__ uint4 lut[256];
    __shared__ unsigned short Bsm[2][64][136];   // [mat][col][k] padded +8

    const int tid = threadIdx.x;
    {
        const unsigned int bb = (unsigned int)tid;
        unsigned int r[4];
        #pragma unroll
        for (int i = 0; i < 4; ++i) {
            const unsigned int b0 = (bb >> (2*i)) & 1u, b1 = (bb >> (2*i+1)) & 1u;
            r[i] = (b0 ? 0x3F80u : 0u) | (b1 ? 0x3F800000u : 0u);
        }
        lut[tid] = make_uint4(r[0], r[1], r[2], r[3]);
    }

    const int w = tid >> 6, lane = tid & 63;
    const int r16 = lane & 15, q = lane >> 4;
    const int PT = P * T;
    const int rowblk = blockIdx.x * 256 + w * 64;
    const int cb = blockIdx.y * 64;

    const uint4* aptr[4];
    #pragma unroll
    for (int f = 0; f < 4; ++f) {
        const int r = rowblk + f*16 + r16;
        const int b = r / PT;
        const int within = r - b * PT;
        const int grow = (b * S + s0) * T + within;
        aptr[f] = masks128 + (size_t)grow * 8;
    }

    const int sflat0 = tid;
    floatx4 acc[4][4];
    #pragma unroll
    for (int f = 0; f < 4; ++f)
        #pragma unroll
        for (int c = 0; c < 4; ++c)
            acc[f][c] = (floatx4){0.f, 0.f, 0.f, 0.f};

    for (int ch = 0; ch < 8; ++ch) {
        __syncthreads();
        #pragma unroll
        for (int i = 0; i < 8; ++i) {
            const int flat = sflat0 + i * 256;      // [mat(1)|col(6)|k16(4)]
            const int mat  = flat >> 10;
            const int rest = flat & 1023;
            const int col  = rest >> 4;
            const int k16  = rest & 15;
            const unsigned short* src =
                (mat ? WlT : WhT) + (size_t)(cb + col) * NIN + ch * 128 + k16 * 8;
            *(uint4*)&Bsm[mat][col][k16 * 8] = *(const uint4*)src;
        }
        uint4 aw[4];
        #pragma unroll
        for (int f = 0; f < 4; ++f) aw[f] = aptr[f][ch];
        __syncthreads();

        #pragma unroll
        for (int kc = 0; kc < 4; ++kc) {
            short8 bh[4], bl[4];
            #pragma unroll
            for (int c = 0; c < 4; ++c) {
                bh[c] = *(const short8*)&Bsm[0][c*16 + r16][kc*32 + q*8];
                bl[c] = *(const short8*)&Bsm[1][c*16 + r16][kc*32 + q*8];
            }
            #pragma unroll
            for (int f = 0; f < 4; ++f) {
                const unsigned int word = (kc == 0) ? aw[f].x : (kc == 1) ? aw[f].y
                                         : (kc == 2) ? aw[f].z : aw[f].w;
                const unsigned int byte = (word >> (q * 8)) & 0xFFu;
                const short8 a = *(const short8*)&lut[byte];
                #pragma unroll
                for (int c = 0; c < 4; ++c) {
                    acc[f][c] = __builtin_amdgcn_mfma_f32_16x16x32_bf16(a, bh[c], acc[f][c], 0, 0, 0);
                    acc[f][c] = __builtin_amdgcn_mfma_f32_16x16x32_bf16(a, bl[c], acc[f][c], 0, 0, 0);
                }
            }
        }
    }

    #pragma unroll
    for (int f = 0; f < 4; ++f) {
        const int row = rowblk + f*16 + q*4;
        #pragma unroll
        for (int c = 0; c < 4; ++c) {
            const int col = cb + c*16 + r16;
            #pragma unroll
            for (int i = 0; i < 4; ++i)
                Iout[(size_t)(row + i) * NOUT + col] = acc[f][c][i];
        }
    }
}

// ---------------------------------------------------------------------------
// Output-population LIF, software-pipelined: prefetch position sl+1's 32
// currents into registers while the serial chain consumes position sl.
// ---------------------------------------------------------------------------
__global__ __launch_bounds__(256) void k_lif_out(const float* __restrict__ Iout,
                                                 float* __restrict__ vstate,
                                                 float* __restrict__ sacc_out,
                                                 unsigned int* __restrict__ counters,
                                                 int s0, int P, int init)
{
    const int tid = blockIdx.x * 256 + threadIdx.x;
    const int b = tid >> 10, n = tid & (NOUT - 1);
    const int Tc = P * T;
    float v = init ? 0.f : vstate[tid];
    const float* ip = Iout + (size_t)b * Tc * NOUT + n;
    int cnt = 0;

    float cur[T];
    #pragma unroll
    for (int t = 0; t < T; ++t) cur[t] = ip[(size_t)t * NOUT];

    for (int sl = 0; sl < P; ++sl) {
        float nxt[T];
        const bool has = (sl + 1 < P);
        if (has) {
            const float* ip2 = ip + (size_t)(sl + 1) * T * NOUT;
            #pragma unroll
            for (int t = 0; t < T; ++t) nxt[t] = ip2[(size_t)t * NOUT];
        }
        float sacc = 0.f;
        #pragma unroll
        for (int t = 0; t < T; ++t) {
            v = __fadd_rn(__fmul_rn(0.9f, v), cur[t]);
            const bool sp = (v >= 1.0f);
            v = sp ? (v - 1.0f) : v;
            sacc += sp ? 1.f : 0.f;
            cnt += sp ? 1 : 0;
        }
        sacc_out[(size_t)(b*S + s0 + sl) * NOUT + n] = sacc;
        if (has) {
            #pragma unroll
            for (int t = 0; t < T; ++t) cur[t] = nxt[t];
        }
    }
    vstate[tid] = v;
    atomicAdd(counters + 1, (unsigned int)cnt);
}

__global__ void k_init(unsigned int* c)
{
    if (threadIdx.x < 2) c[threadIdx.x] = 0u;
}

__global__ void k_rate(const unsigned int* __restrict__ c, float* __restrict__ out)
{
    if (threadIdx.x == 0 && blockIdx.x == 0) {
        const float total = (float)c[0] + (float)c[1];
        out[0] = total / (float)(B * S * (NIN + NOUT) * T);
    }
}

// ---------------------------------------------------------------------------
extern "C" void kernel_launch(void* const* d_in, const int* in_sizes, int n_in,
                              void* d_out, int out_size, void* d_ws, size_t ws_size,
                              hipStream_t stream)
{
    const float* E    = (const float*)d_in[0];
    const float* Win  = (const float*)d_in[1];
    const float* bin  = (const float*)d_in[2];
    const float* Wc   = (const float*)d_in[3];
    const float* Wout = (const float*)d_in[4];
    const float* bout = (const float*)d_in[5];
    float* out = (float*)d_out;

    char* w = (char*)d_ws;
    float* snn              = (float*)(w);                          // 4 MB (later reused for WcT)
    unsigned short* WhT     = (unsigned short*)(w);                 // 2 MB (aliases snn, after lif_inA)
    unsigned short* WlT     = (unsigned short*)(w + (2 << 20));     // 2 MB
    unsigned long long* msk = (unsigned long long*)(w + (4 << 20)); // 4 MB
    float* sacc             = (float*)(w + (8 << 20));              // 4 MB
    unsigned int* sbits     = (unsigned int*)(w + (8 << 20));       // 4 MB (aliases sacc; dead before lif_out)
    float* vst              = (float*)(w + (12 << 20));             // 32 KB
    unsigned int* cnt       = (unsigned int*)(w + (12 << 20) + (64 << 10));
    float* Iout             = (float*)(w + (13 << 20));

    const size_t base = (size_t)13 << 20;
    const size_t avail = (ws_size > base) ? (ws_size - base) : 0;
    int P = 1;
    if      (avail >= (size_t)B * 128 * T * NOUT * 4) P = 128;
    else if (avail >= (size_t)B *  16 * T * NOUT * 4) P = 16;
    else if (avail >= (size_t)B *   4 * T * NOUT * 4) P = 4;

    k_init<<<1, 64, 0, stream>>>(cnt);

    dim3 g1(NIN / 64, (B * S) / 64);
    k_gemm<<<g1, 256, 0, stream>>>(E, Win, bin, snn, B * S, NIN, D, 1);

    k_lif_inA<<<32, 256, 0, stream>>>(snn, sbits, cnt);
    k_lif_inB<<<B * S, 256, 0, stream>>>(sbits, msk);

    // snn is dead now: build transposed hi/lo bf16 split of W_conn in its place
    dim3 gp(NIN / 64, NOUT / 64);
    k_prep<<<gp, 256, 0, stream>>>(Wc, WhT, WlT);

    for (int c = 0; c < S / P; ++c) {
        dim3 gc((B * P * T) / 256, NOUT / 64);
        k_conn_mfma<<<gc, 256, 0, stream>>>((const uint4*)msk, WhT, WlT, Iout, c * P, P);
        k_lif_out<<<32, 256, 0, stream>>>(Iout, vst, sacc, cnt, c * P, P, c == 0 ? 1 : 0);
    }

    dim3 g2(D / 64, (B * S) / 64);
    k_gemm<<<g2, 256, 0, stream>>>(sacc, Wout, bout, out, B * S, D, NOUT, 0);

    k_rate<<<1, 64, 0, stream>>>(cnt, out + (size_t)B * S * D);
}